// Round 4
// baseline (438.875 us; speedup 1.0000x reference)
//
#include <hip/hip_runtime.h>
#include <math.h>

#define FF 128     // feature width (all layers)
#define CAP 32     // slots per (relation,node); Poisson(4) => P(deg>32) ~ 1e-19
#define G0 2048    // gemm0 grid   (R17: 8 blocks/CU tail, packed-B makes this cheap)
#define GG 2048    // mfma_gemm grid (R17: 512->2048, same argument)

typedef _Float16 half2v __attribute__((ext_vector_type(2)));
typedef _Float16 f16x8  __attribute__((ext_vector_type(8)));
typedef __fp16   fp16x2 __attribute__((ext_vector_type(2)));
typedef __attribute__((ext_vector_type(4))) float f4v;

__device__ __forceinline__ half2v u2h(unsigned u) {
    union { unsigned u; half2v h; } c; c.u = u; return c.h;
}
__device__ __forceinline__ unsigned h2u(half2v h) {
    union { unsigned u; half2v h; } c; c.h = h; return c.u;
}
__device__ __forceinline__ unsigned short f2h(float f) {
    _Float16 h = (_Float16)f;
    unsigned short u; __builtin_memcpy(&u, &h, 2); return u;
}
__device__ __forceinline__ half2v pk2h(float e) {
    union { fp16x2 p; half2v h; } c;
    c.p = __builtin_amdgcn_cvt_pkrtz(e, e);
    return c.h;
}
__device__ __forceinline__ float dot2(half2v a, half2v b, float c) {
#if __has_builtin(__builtin_amdgcn_fdot2)
    union { half2v h; fp16x2 p; } ca, cb;
    ca.h = a; cb.h = b;
    return __builtin_amdgcn_fdot2(ca.p, cb.p, c, false);
#else
    return c + (float)a.x * (float)b.x + (float)a.y * (float)b.y;
#endif
}
__device__ __forceinline__ half2v shfladd_h(half2v v, int mask) {
    return v + u2h(__shfl_xor(h2u(v), mask));
}
__device__ __forceinline__ int qsel(int4 v, int quarter) {
    return (quarter == 0) ? v.x : (quarter == 1) ? v.y
         : (quarter == 2) ? v.z : v.w;
}
// 16B-chunk XOR swizzle inside a [16 rows][256B] LDS tile.
__device__ __forceinline__ int swz16(int row, int chunk) {
    return row * 256 + (((chunk ^ row) & 15) << 4);
}

// =====================================================================
// R17: fused setup SPLIT. R14/R15/R16 post-mortems: occupancy 20->40%,
// segments cut 5x, grids varied -- setup_fused pinned at ~105us. Four
// falsified theories about the GEMM path => the fused dispatch hides
// which phase owns the time (one counter row, four phases). Split gives
// per-phase counters AND removes the Wp race so gemm0 reads packed B
// (cheap coalesced fill -> grid can scale to 8 blocks/CU, which is what
// R15 fumbled by replicating the strided f32 B-gather).
// =====================================================================

// ---------------- csr_pack: CSR fill + pack W + pack att -------------
__global__ __launch_bounds__(256) void csr_pack(
    const int* __restrict__ esrc_all, const int* __restrict__ edst_all,
    int* __restrict__ cursor, int* __restrict__ slots, int totalE, int ne, int n,
    const float* __restrict__ W0s_, const float* __restrict__ W0d_,
    const float* __restrict__ W1s_, const float* __restrict__ W1d_,
    const float* __restrict__ W2s_, const float* __restrict__ W2d_,
    unsigned short* __restrict__ Wp,
    const float* __restrict__ a0, const float* __restrict__ a1,
    const float* __restrict__ a2, unsigned* __restrict__ attH,
    int CB)
{
    int b = blockIdx.x;
    const int tid = threadIdx.x;

    if (b < CB) {
        // padded-CSR fill, 4 independent chains/thread
        const int t0 = b * 1024 + tid;
        #pragma unroll
        for (int k = 0; k < 4; ++k) {
            const int i = t0 + k * 256;
            if (i < totalE) {
                const int r = i / ne;
                const int rd = r * n + edst_all[i];
                const int idx = atomicAdd(&cursor[rd], 1);
                slots[(size_t)rd * CAP + idx] = esrc_all[i];
            }
        }
        return;
    }
    b -= CB;

    if (b < 1536) {
        // pack W (all 3 layers) into MFMA B-fragment layout
        const int t = b * 256 + tid;
        if (t >= 3 * 4 * 2 * FF * FF) return;
        const int l    = t >> 17;
        const int rest = t & 131071;
        const int r    = rest >> 15;
        const int mat  = (rest >> 14) & 1;
        const int idx  = rest & 16383;
        const int k = idx >> 7, nn = idx & 127;
        const float* W = (l == 0) ? (mat ? W0d_ : W0s_)
                       : (l == 1) ? (mat ? W1d_ : W1s_)
                                  : (mat ? W2d_ : W2s_);
        const float v = W[((size_t)r * FF + k) * FF + nn];
        const int nb = nn >> 4, lo = nn & 15;
        const int ks = k >> 5, quad = (k >> 3) & 3, j = k & 7;
        const int lane = quad * 16 + lo;
        const size_t o = (((((((size_t)l * 4 + r) * 2 + mat) * 8 + nb) * 4 + ks) * 64 + lane) * 8) + j;
        Wp[o] = f2h(v);
        return;
    }
    b -= 1536;

    // pack att
    const int t = b * 256 + tid;
    if (t >= 768) return;
    const int l = t >> 8, rest = t & 255;
    const float* a = (l == 0) ? a0 : (l == 1) ? a1 : a2;
    const float2 v = ((const float2*)a)[rest];
    half2v h = {(_Float16)v.x, (_Float16)v.y};
    attH[t] = h2u(h);
}

// ---------------- gemm0: layer-0 GEMM, f32 activations ---------------
// R16 LDS-staged structure; B from PACKED Wp (layer-0 section), same as
// mfma_gemm. One mat per wave (wave = half x mat), 64 VGPR.
__global__ __launch_bounds__(256, 4) void gemm0(
    const float* __restrict__ x,
    const unsigned short* __restrict__ Wp,      // layer-0 section
    const float* __restrict__ bs0,
    const float* __restrict__ bd0,
    unsigned short* __restrict__ fs_all,
    unsigned short* __restrict__ fd_all,
    int nrb, int n)
{
    __shared__ char lsA[4096];
    __shared__ char lsC[8192];

    const int tid = threadIdx.x;
    const int wave = tid >> 6, lane = tid & 63;
    const int r = blockIdx.x & 3;
    const int half = wave & 1;
    const int mat  = wave >> 1;
    const int lo = lane & 15, quad = lane >> 4;

    const unsigned short* Wr = Wp + (size_t)r * 2 * FF * FF;
    const float* bp = mat ? bd0 : bs0;
    unsigned short* fs = fs_all + (size_t)r * n * FF;
    unsigned short* fd = fd_all + (size_t)r * n * FF;

    f16x8 B[4][4];
    #pragma unroll
    for (int nbi = 0; nbi < 4; ++nbi)
        #pragma unroll
        for (int ks = 0; ks < 4; ++ks) {
            const int nb = half * 4 + nbi;
            B[nbi][ks] = *(const f16x8*)
                &Wr[(((((size_t)mat * 8 + nb) * 4 + ks) * 64 + lane) * 8)];
        }

    float bias[4];
    #pragma unroll
    for (int nbi = 0; nbi < 4; ++nbi)
        bias[nbi] = bp[r * FF + (half * 4 + nbi) * 16 + lo];

    const int srow = tid >> 4, schunk = tid & 15;
    const int stride = gridDim.x >> 2;
    for (int rb = blockIdx.x >> 2; rb < nrb; rb += stride) {
        const int row0 = rb * 16;

        // cooperative coalesced stage: x (f32) -> lsA (f16)
        {
            const float* xs = &x[(size_t)row0 * FF + tid * 8];
            const float4 p0 = *(const float4*)&xs[0];
            const float4 p1 = *(const float4*)&xs[4];
            f16x8 v;
            v[0] = (_Float16)p0.x; v[1] = (_Float16)p0.y;
            v[2] = (_Float16)p0.z; v[3] = (_Float16)p0.w;
            v[4] = (_Float16)p1.x; v[5] = (_Float16)p1.y;
            v[6] = (_Float16)p1.z; v[7] = (_Float16)p1.w;
            *(f16x8*)&lsA[swz16(srow, schunk)] = v;
        }
        __syncthreads();

        f16x8 A[4];
        #pragma unroll
        for (int ks = 0; ks < 4; ++ks)
            A[ks] = *(const f16x8*)&lsA[swz16(lo, ks * 4 + quad)];

        f4v c[4];
        #pragma unroll
        for (int nbi = 0; nbi < 4; ++nbi)
            c[nbi] = (f4v){bias[nbi], bias[nbi], bias[nbi], bias[nbi]};

        #pragma unroll
        for (int ks = 0; ks < 4; ++ks)
            #pragma unroll
            for (int nbi = 0; nbi < 4; ++nbi)
                c[nbi] = __builtin_amdgcn_mfma_f32_16x16x32_f16(
                    A[ks], B[nbi][ks], c[nbi], 0, 0, 0);

        #pragma unroll
        for (int nbi = 0; nbi < 4; ++nbi)
            #pragma unroll
            for (int i = 0; i < 4; ++i) {
                const int row = quad * 4 + i;
                const int cb  = ((half * 4 + nbi) * 16 + lo) * 2;
                *(unsigned short*)&lsC[mat * 4096 + swz16(row, cb >> 4) + (cb & 15)]
                    = f2h(c[nbi][i]);
            }
        __syncthreads();

        #pragma unroll
        for (int p = 0; p < 2; ++p) {
            const int unit = p * 256 + tid;
            const int m    = unit >> 8;
            const int row  = (unit >> 4) & 15;
            const int ch   = unit & 15;
            const uint4 d = *(const uint4*)&lsC[m * 4096 + swz16(row, ch)];
            unsigned short* out = m ? fd : fs;
            *(uint4*)&out[(size_t)(row0 + row) * FF + ch * 8] = d;
        }
        __syncthreads();
    }
}

// =====================================================================
// Batched MFMA GEMM over all 4 relations, f16 inputs (layers 1,2).
// R16 LDS-staged structure; R17: grid 512->2048.
// =====================================================================
__global__ __launch_bounds__(256, 4) void mfma_gemm(
    const unsigned short* __restrict__ hb,
    const unsigned short* __restrict__ Wp,
    const float* __restrict__ bs_all,
    const float* __restrict__ bd_all,
    unsigned short* __restrict__ fs_all,
    unsigned short* __restrict__ fd_all,
    int nrb, int n)
{
    __shared__ char lsA[4096];
    __shared__ char lsC[8192];

    const int tid = threadIdx.x;
    const int wave = tid >> 6, lane = tid & 63;
    const int r = blockIdx.x & 3;
    const int half = wave & 1;
    const int mat  = wave >> 1;
    const int lo = lane & 15, quad = lane >> 4;

    const unsigned short* Wr = Wp + (size_t)r * 2 * FF * FF;
    const float* bp = mat ? bd_all : bs_all;
    unsigned short* fs = fs_all + (size_t)r * n * FF;
    unsigned short* fd = fd_all + (size_t)r * n * FF;

    f16x8 B[4][4];
    #pragma unroll
    for (int nbi = 0; nbi < 4; ++nbi)
        #pragma unroll
        for (int ks = 0; ks < 4; ++ks) {
            const int nb = half * 4 + nbi;
            B[nbi][ks] = *(const f16x8*)
                &Wr[(((((size_t)mat * 8 + nb) * 4 + ks) * 64 + lane) * 8)];
        }

    float bias[4];
    #pragma unroll
    for (int nbi = 0; nbi < 4; ++nbi)
        bias[nbi] = bp[r * FF + (half * 4 + nbi) * 16 + lo];

    const int srow = tid >> 4, schunk = tid & 15;
    const int stride = gridDim.x >> 2;
    for (int rb = blockIdx.x >> 2; rb < nrb; rb += stride) {
        const int row0 = rb * 16;

        {
            const uint4 g = *(const uint4*)&hb[(size_t)row0 * FF + tid * 8];
            *(uint4*)&lsA[swz16(srow, schunk)] = g;
        }
        __syncthreads();

        f16x8 A[4];
        #pragma unroll
        for (int ks = 0; ks < 4; ++ks)
            A[ks] = *(const f16x8*)&lsA[swz16(lo, ks * 4 + quad)];

        f4v c[4];
        #pragma unroll
        for (int nbi = 0; nbi < 4; ++nbi)
            c[nbi] = (f4v){bias[nbi], bias[nbi], bias[nbi], bias[nbi]};

        #pragma unroll
        for (int ks = 0; ks < 4; ++ks)
            #pragma unroll
            for (int nbi = 0; nbi < 4; ++nbi)
                c[nbi] = __builtin_amdgcn_mfma_f32_16x16x32_f16(
                    A[ks], B[nbi][ks], c[nbi], 0, 0, 0);

        #pragma unroll
        for (int nbi = 0; nbi < 4; ++nbi)
            #pragma unroll
            for (int i = 0; i < 4; ++i) {
                const int row = quad * 4 + i;
                const int cb  = ((half * 4 + nbi) * 16 + lo) * 2;
                *(unsigned short*)&lsC[mat * 4096 + swz16(row, cb >> 4) + (cb & 15)]
                    = f2h(c[nbi][i]);
            }
        __syncthreads();

        #pragma unroll
        for (int p = 0; p < 2; ++p) {
            const int unit = p * 256 + tid;
            const int m    = unit >> 8;
            const int row  = (unit >> 4) & 15;
            const int ch   = unit & 15;
            const uint4 d = *(const uint4*)&lsC[m * 4096 + swz16(row, ch)];
            unsigned short* out = m ? fd : fs;
            *(uint4*)&out[(size_t)(row0 + row) * FF + ch * 8] = d;
        }
        __syncthreads();
    }
}

// =====================================================================
// Fused aggregate, quarter-wave per edge. R13 structure, unchanged.
// =====================================================================
__device__ __forceinline__ void edge4(
    uint4 g, bool ok, const half2v* fdv, const half2v* atv,
    float& den, half2v* acc)
{
    const half2v C02 = {(_Float16)0.2f, (_Float16)0.2f};
    half2v f[4] = {u2h(g.x), u2h(g.y), u2h(g.z), u2h(g.w)};
    float v = 0.f;
    #pragma unroll
    for (int i = 0; i < 4; ++i) {
        const half2v z = f[i] + fdv[i];
        const half2v l = __builtin_elementwise_max(z, z * C02);
        v = dot2(l, atv[i], v);
    }
    v += __shfl_xor(v, 2);
    v += __shfl_xor(v, 1);
    const float e = ok ? __expf(v) : 0.f;
    den += e;
    const half2v eh = pk2h(e);
    #pragma unroll
    for (int i = 0; i < 4; ++i) acc[i] += eh * f[i];
}

__global__ __launch_bounds__(256) void aggregate(
    const int* __restrict__ cnt,             // [R*n]
    const int* __restrict__ slots,           // [R*n][CAP]
    const unsigned* __restrict__ fs_all,     // [R][n][64] f16 pairs
    const unsigned* __restrict__ fd_all,
    const unsigned* __restrict__ att_h,      // this layer: [R][64] f16 pairs
    unsigned* __restrict__ out_h,            // [n][64] or null
    float* __restrict__ out_f32,             // [n][32] or null
    int n)
{
    const int node = blockIdx.x * 4 + (threadIdx.x >> 6);
    if (node >= n) return;
    const int lane = threadIdx.x & 63;
    const int quarter = lane >> 4;
    const int q = lane & 15;
    const int fo = 4 * q;

    int m[4]; int4 sA[4];
    #pragma unroll
    for (int r = 0; r < 4; ++r) {
        const size_t rd = (size_t)r * n + node;
        m[r]  = cnt[rd];
        sA[r] = *(const int4*)&slots[rd * CAP];
    }

    half2v val[4];
    #pragma unroll
    for (int i = 0; i < 4; ++i) val[i] = (half2v){(_Float16)0.f, (_Float16)0.f};

    #pragma unroll
    for (int rp = 0; rp < 2; ++rp) {
        const int ra = 2 * rp, rb = 2 * rp + 1;
        const size_t rdA = (size_t)ra * n + node;
        const size_t rdB = (size_t)rb * n + node;
        const int mA = m[ra], mB = m[rb];
        const unsigned* fsuA = fs_all + (size_t)ra * n * 64;
        const unsigned* fsuB = fs_all + (size_t)rb * n * 64;

        // ---- issue ALL loads for both relations up front ----
        const int4 sBA = *(const int4*)&slots[rdA * CAP + 4];
        const int4 sBB = *(const int4*)&slots[rdB * CAP + 4];
        const uint4 ufdA = *(const uint4*)&fd_all[rdA * 64 + fo];
        const uint4 ufdB = *(const uint4*)&fd_all[rdB * 64 + fo];
        const uint4 uatA = *(const uint4*)&att_h[ra * 64 + fo];
        const uint4 uatB = *(const uint4*)&att_h[rb * 64 + fo];

        const bool okA0 = quarter < mA, okA1 = 4 + quarter < mA;
        const bool okB0 = quarter < mB, okB1 = 4 + quarter < mB;
        int iA0 = qsel(sA[ra], quarter); iA0 = okA0 ? iA0 : 0;
        int iB0 = qsel(sA[rb], quarter); iB0 = okB0 ? iB0 : 0;
        int iA1 = qsel(sBA, quarter);    iA1 = okA1 ? iA1 : 0;
        int iB1 = qsel(sBB, quarter);    iB1 = okB1 ? iB1 : 0;
        const uint4 gA0 = *(const uint4*)&fsuA[(size_t)iA0 * 64 + fo];
        const uint4 gB0 = *(const uint4*)&fsuB[(size_t)iB0 * 64 + fo];
        const uint4 gA1 = *(const uint4*)&fsuA[(size_t)iA1 * 64 + fo];
        const uint4 gB1 = *(const uint4*)&fsuB[(size_t)iB1 * 64 + fo];

        half2v fdvA[4] = {u2h(ufdA.x), u2h(ufdA.y), u2h(ufdA.z), u2h(ufdA.w)};
        half2v atvA[4] = {u2h(uatA.x), u2h(uatA.y), u2h(uatA.z), u2h(uatA.w)};
        half2v fdvB[4] = {u2h(ufdB.x), u2h(ufdB.y), u2h(ufdB.z), u2h(ufdB.w)};
        half2v atvB[4] = {u2h(uatB.x), u2h(uatB.y), u2h(uatB.z), u2h(uatB.w)};

        float denA = 0.f, denB = 0.f;
        half2v accA[4], accB[4];
        #pragma unroll
        for (int i = 0; i < 4; ++i) {
            accA[i] = (half2v){(_Float16)0.f, (_Float16)0.f};
            accB[i] = (half2v){(_Float16)0.f, (_Float16)0.f};
        }

        edge4(gA0, okA0, fdvA, atvA, denA, accA);
        edge4(gB0, okB0, fdvB, atvB, denB, accB);
        if (mA > 4) edge4(gA1, okA1, fdvA, atvA, denA, accA);
        if (mB > 4) edge4(gB1, okB1, fdvB, atvB, denB, accB);

        if (mA > 8) {                        // P ~ 2%
            const int* sl = slots + rdA * CAP;
            for (int p = 8; p < mA; p += 4) {
                const int ei = p + quarter;
                const bool ok = ei < mA;
                int s = sl[ei < CAP ? ei : CAP - 1]; s = ok ? s : 0;
                const uint4 g = *(const uint4*)&fsuA[(size_t)s * 64 + fo];
                edge4(g, ok, fdvA, atvA, denA, accA);
            }
        }
        if (mB > 8) {
            const int* sl = slots + rdB * CAP;
            for (int p = 8; p < mB; p += 4) {
                const int ei = p + quarter;
                const bool ok = ei < mB;
                int s = sl[ei < CAP ? ei : CAP - 1]; s = ok ? s : 0;
                const uint4 g = *(const uint4*)&fsuB[(size_t)s * 64 + fo];
                edge4(g, ok, fdvB, atvB, denB, accB);
            }
        }

        if (mA) {
            denA += __shfl_xor(denA, 16);
            denA += __shfl_xor(denA, 32);
            const half2v ih = pk2h(__builtin_amdgcn_rcpf(denA));   // denA > 0
            #pragma unroll
            for (int i = 0; i < 4; ++i) val[i] += accA[i] * ih;
        }
        if (mB) {
            denB += __shfl_xor(denB, 16);
            denB += __shfl_xor(denB, 32);
            const half2v ih = pk2h(__builtin_amdgcn_rcpf(denB));   // denB > 0
            #pragma unroll
            for (int i = 0; i < 4; ++i) val[i] += accB[i] * ih;
        }
    }

    // combine quarters' numerator contributions (packed)
    #pragma unroll
    for (int i = 0; i < 4; ++i) {
        val[i] = shfladd_h(val[i], 16);
        val[i] = shfladd_h(val[i], 32);
    }

    if (out_f32) {
        // mean over heads: lane q holds feats 8q..8q+7, head = q>>2;
        // orbit masks 4, 8 (packed)
        #pragma unroll
        for (int i = 0; i < 4; ++i) {
            val[i] = shfladd_h(val[i], 4);
            val[i] = shfladd_h(val[i], 8);
        }
        if (lane < 4) {
            float* o = &out_f32[(size_t)node * 32 + 8 * lane];
            *(float4*)&o[0] = make_float4(0.25f * (float)val[0].x, 0.25f * (float)val[0].y,
                                          0.25f * (float)val[1].x, 0.25f * (float)val[1].y);
            *(float4*)&o[4] = make_float4(0.25f * (float)val[2].x, 0.25f * (float)val[2].y,
                                          0.25f * (float)val[3].x, 0.25f * (float)val[3].y);
        }
    } else {
        if (lane < 16) {
            uint4 o;
            o.x = h2u(val[0]); o.y = h2u(val[1]);
            o.z = h2u(val[2]); o.w = h2u(val[3]);
            *(uint4*)&out_h[(size_t)node * 64 + fo] = o;
        }
    }
}

// =====================================================================
extern "C" void kernel_launch(void* const* d_in, const int* in_sizes, int n_in,
                              void* d_out, int out_size, void* d_ws, size_t ws_size,
                              hipStream_t stream)
{
    const int n  = in_sizes[0] / FF;     // 50000
    const int R  = 4;
    const int ne = in_sizes[1] / R;      // 200000
    const int totalE = R * ne;
    const int L  = R * n;
    const int nrb = (n + 15) / 16;

    const float* x    = (const float*)d_in[0];
    const int*   esrc = (const int*)d_in[1];
    const int*   edst = (const int*)d_in[2];

    // ---- workspace layout (~142 MB of ~268 MB ws) ----
    char* p = (char*)d_ws;
    auto carve = [&p](size_t bytes) { char* q = p; p += (bytes + 255) & ~(size_t)255; return q; };
    unsigned*       hbA    = (unsigned*)      carve((size_t)n * 64 * 4);
    unsigned*       hbB    = (unsigned*)      carve((size_t)n * 64 * 4);
    unsigned short* fs_all = (unsigned short*)carve((size_t)R * n * FF * 2);
    unsigned short* fd_all = (unsigned short*)carve((size_t)R * n * FF * 2);
    unsigned short* Wp     = (unsigned short*)carve((size_t)3 * R * 2 * FF * FF * 2);
    unsigned*       attH   = (unsigned*)      carve((size_t)3 * R * 64 * 4);
    int*            cursor = (int*)           carve((size_t)L * 4);
    int*            slots  = (int*)           carve((size_t)L * CAP * 4);

    (void)hipMemsetAsync(cursor, 0, (size_t)L * sizeof(int), stream);

    // ---- phase 1: CSR fill + pack W + pack att ----
    const int CB = (totalE + 1023) / 1024;
    csr_pack<<<CB + 1536 + 3, 256, 0, stream>>>(
        esrc, edst, cursor, slots, totalE, ne, n,
        (const float*)d_in[3],  (const float*)d_in[5],
        (const float*)d_in[8],  (const float*)d_in[10],
        (const float*)d_in[13], (const float*)d_in[15],
        Wp,
        (const float*)d_in[7], (const float*)d_in[12], (const float*)d_in[17],
        attH, CB);

    // ---- phase 2: layer-0 GEMM from packed Wp ----
    gemm0<<<G0, 256, 0, stream>>>(
        x, Wp,
        (const float*)d_in[4], (const float*)d_in[6],
        fs_all, fd_all, nrb, n);

    // ---- layers ----
    unsigned* bufs[3] = {hbA, hbB, nullptr};
    for (int l = 0; l < 3; ++l) {
        if (l > 0) {
            const float* bsrc = (const float*)d_in[3 + 5 * l + 1];
            const float* bdst = (const float*)d_in[3 + 5 * l + 3];
            mfma_gemm<<<GG, 256, 0, stream>>>(
                (const unsigned short*)bufs[l - 1],
                Wp + (size_t)l * R * 2 * FF * FF,
                bsrc, bdst, fs_all, fd_all, nrb, n);
        }
        const int last = (l == 2);
        aggregate<<<(n + 3) / 4, 256, 0, stream>>>(
            cursor, slots,
            (const unsigned*)fs_all, (const unsigned*)fd_all,
            attH + (size_t)l * R * 64,
            last ? nullptr : bufs[l],
            last ? (float*)d_out : nullptr, n);
    }
}

// Round 5
// 409.029 us; speedup vs baseline: 1.0730x; 1.0730x over previous
//
#include <hip/hip_runtime.h>
#include <math.h>

#define FF 128     // feature width (all layers)
#define CAP 32     // slot planes per relation-node; Poisson(4) => P(deg>32) ~ 1e-19
#define G0 2048    // gemm0 grid
#define GG 2048    // mfma_gemm grid

typedef _Float16 half2v __attribute__((ext_vector_type(2)));
typedef _Float16 f16x8  __attribute__((ext_vector_type(8)));
typedef __fp16   fp16x2 __attribute__((ext_vector_type(2)));
typedef __attribute__((ext_vector_type(4))) float f4v;

__device__ __forceinline__ half2v u2h(unsigned u) {
    union { unsigned u; half2v h; } c; c.u = u; return c.h;
}
__device__ __forceinline__ unsigned h2u(half2v h) {
    union { unsigned u; half2v h; } c; c.h = h; return c.u;
}
__device__ __forceinline__ unsigned short f2h(float f) {
    _Float16 h = (_Float16)f;
    unsigned short u; __builtin_memcpy(&u, &h, 2); return u;
}
__device__ __forceinline__ half2v pk2h(float e) {
    union { fp16x2 p; half2v h; } c;
    c.p = __builtin_amdgcn_cvt_pkrtz(e, e);
    return c.h;
}
__device__ __forceinline__ float dot2(half2v a, half2v b, float c) {
#if __has_builtin(__builtin_amdgcn_fdot2)
    union { half2v h; fp16x2 p; } ca, cb;
    ca.h = a; cb.h = b;
    return __builtin_amdgcn_fdot2(ca.p, cb.p, c, false);
#else
    return c + (float)a.x * (float)b.x + (float)a.y * (float)b.y;
#endif
}
__device__ __forceinline__ half2v shfladd_h(half2v v, int mask) {
    return v + u2h(__shfl_xor(h2u(v), mask));
}
// 16B-chunk XOR swizzle inside a [16 rows][256B] LDS tile.
__device__ __forceinline__ int swz16(int row, int chunk) {
    return row * 256 + (((chunk ^ row) & 15) << 4);
}

// =====================================================================
// R18: slots layout TRANSPOSED to plane-major slots[idx][R*n].
// R17 post-mortem: csr_pack = 76us with WRITE_SIZE 51.4MB vs 3.2MB of
// useful slot data -- 16x write amplification from scattered 4B stores
// into sparse [rd][CAP] rows (each store dirties a 64B line, 800k lines
// written back). Plane-major: plane k holds the k-th edge of EVERY
// (r,node) -- plane 0 is 98% occupied, plane 1 91%... so dirtied lines
// are nearly fully useful. Expected write-back ~5MB. Aggregate gets
// simpler: lane of quarter q only needs planes q,4+q,8+q..., a direct
// per-lane load (qsel shuffle-select deleted).
// =====================================================================

// ---------------- csr_pack: CSR fill + pack W + pack att -------------
__global__ __launch_bounds__(256) void csr_pack(
    const int* __restrict__ esrc_all, const int* __restrict__ edst_all,
    int* __restrict__ cursor, int* __restrict__ slots, int totalE, int ne, int n,
    const float* __restrict__ W0s_, const float* __restrict__ W0d_,
    const float* __restrict__ W1s_, const float* __restrict__ W1d_,
    const float* __restrict__ W2s_, const float* __restrict__ W2d_,
    unsigned short* __restrict__ Wp,
    const float* __restrict__ a0, const float* __restrict__ a1,
    const float* __restrict__ a2, unsigned* __restrict__ attH,
    int CB)
{
    int b = blockIdx.x;
    const int tid = threadIdx.x;
    const int L4 = n << 2;               // plane stride (R*n)

    if (b < CB) {
        // padded-CSR fill, 4 independent chains/thread, plane-major store
        const int t0 = b * 1024 + tid;
        #pragma unroll
        for (int k = 0; k < 4; ++k) {
            const int i = t0 + k * 256;
            if (i < totalE) {
                const int r = i / ne;
                const int rd = r * n + edst_all[i];
                const int idx = atomicAdd(&cursor[rd], 1);
                slots[(size_t)idx * L4 + rd] = esrc_all[i];
            }
        }
        return;
    }
    b -= CB;

    if (b < 1536) {
        // pack W (all 3 layers) into MFMA B-fragment layout
        const int t = b * 256 + tid;
        if (t >= 3 * 4 * 2 * FF * FF) return;
        const int l    = t >> 17;
        const int rest = t & 131071;
        const int r    = rest >> 15;
        const int mat  = (rest >> 14) & 1;
        const int idx  = rest & 16383;
        const int k = idx >> 7, nn = idx & 127;
        const float* W = (l == 0) ? (mat ? W0d_ : W0s_)
                       : (l == 1) ? (mat ? W1d_ : W1s_)
                                  : (mat ? W2d_ : W2s_);
        const float v = W[((size_t)r * FF + k) * FF + nn];
        const int nb = nn >> 4, lo = nn & 15;
        const int ks = k >> 5, quad = (k >> 3) & 3, j = k & 7;
        const int lane = quad * 16 + lo;
        const size_t o = (((((((size_t)l * 4 + r) * 2 + mat) * 8 + nb) * 4 + ks) * 64 + lane) * 8) + j;
        Wp[o] = f2h(v);
        return;
    }
    b -= 1536;

    // pack att
    const int t = b * 256 + tid;
    if (t >= 768) return;
    const int l = t >> 8, rest = t & 255;
    const float* a = (l == 0) ? a0 : (l == 1) ? a1 : a2;
    const float2 v = ((const float2*)a)[rest];
    half2v h = {(_Float16)v.x, (_Float16)v.y};
    attH[t] = h2u(h);
}

// ---------------- gemm0: layer-0 GEMM, f32 activations ---------------
__global__ __launch_bounds__(256, 4) void gemm0(
    const float* __restrict__ x,
    const unsigned short* __restrict__ Wp,      // layer-0 section
    const float* __restrict__ bs0,
    const float* __restrict__ bd0,
    unsigned short* __restrict__ fs_all,
    unsigned short* __restrict__ fd_all,
    int nrb, int n)
{
    __shared__ char lsA[4096];
    __shared__ char lsC[8192];

    const int tid = threadIdx.x;
    const int wave = tid >> 6, lane = tid & 63;
    const int r = blockIdx.x & 3;
    const int half = wave & 1;
    const int mat  = wave >> 1;
    const int lo = lane & 15, quad = lane >> 4;

    const unsigned short* Wr = Wp + (size_t)r * 2 * FF * FF;
    const float* bp = mat ? bd0 : bs0;
    unsigned short* fs = fs_all + (size_t)r * n * FF;
    unsigned short* fd = fd_all + (size_t)r * n * FF;

    f16x8 B[4][4];
    #pragma unroll
    for (int nbi = 0; nbi < 4; ++nbi)
        #pragma unroll
        for (int ks = 0; ks < 4; ++ks) {
            const int nb = half * 4 + nbi;
            B[nbi][ks] = *(const f16x8*)
                &Wr[(((((size_t)mat * 8 + nb) * 4 + ks) * 64 + lane) * 8)];
        }

    float bias[4];
    #pragma unroll
    for (int nbi = 0; nbi < 4; ++nbi)
        bias[nbi] = bp[r * FF + (half * 4 + nbi) * 16 + lo];

    const int srow = tid >> 4, schunk = tid & 15;
    const int stride = gridDim.x >> 2;
    for (int rb = blockIdx.x >> 2; rb < nrb; rb += stride) {
        const int row0 = rb * 16;

        {
            const float* xs = &x[(size_t)row0 * FF + tid * 8];
            const float4 p0 = *(const float4*)&xs[0];
            const float4 p1 = *(const float4*)&xs[4];
            f16x8 v;
            v[0] = (_Float16)p0.x; v[1] = (_Float16)p0.y;
            v[2] = (_Float16)p0.z; v[3] = (_Float16)p0.w;
            v[4] = (_Float16)p1.x; v[5] = (_Float16)p1.y;
            v[6] = (_Float16)p1.z; v[7] = (_Float16)p1.w;
            *(f16x8*)&lsA[swz16(srow, schunk)] = v;
        }
        __syncthreads();

        f16x8 A[4];
        #pragma unroll
        for (int ks = 0; ks < 4; ++ks)
            A[ks] = *(const f16x8*)&lsA[swz16(lo, ks * 4 + quad)];

        f4v c[4];
        #pragma unroll
        for (int nbi = 0; nbi < 4; ++nbi)
            c[nbi] = (f4v){bias[nbi], bias[nbi], bias[nbi], bias[nbi]};

        #pragma unroll
        for (int ks = 0; ks < 4; ++ks)
            #pragma unroll
            for (int nbi = 0; nbi < 4; ++nbi)
                c[nbi] = __builtin_amdgcn_mfma_f32_16x16x32_f16(
                    A[ks], B[nbi][ks], c[nbi], 0, 0, 0);

        #pragma unroll
        for (int nbi = 0; nbi < 4; ++nbi)
            #pragma unroll
            for (int i = 0; i < 4; ++i) {
                const int row = quad * 4 + i;
                const int cb  = ((half * 4 + nbi) * 16 + lo) * 2;
                *(unsigned short*)&lsC[mat * 4096 + swz16(row, cb >> 4) + (cb & 15)]
                    = f2h(c[nbi][i]);
            }
        __syncthreads();

        #pragma unroll
        for (int p = 0; p < 2; ++p) {
            const int unit = p * 256 + tid;
            const int m    = unit >> 8;
            const int row  = (unit >> 4) & 15;
            const int ch   = unit & 15;
            const uint4 d = *(const uint4*)&lsC[m * 4096 + swz16(row, ch)];
            unsigned short* out = m ? fd : fs;
            *(uint4*)&out[(size_t)(row0 + row) * FF + ch * 8] = d;
        }
        __syncthreads();
    }
}

// =====================================================================
// Batched MFMA GEMM over all 4 relations, f16 inputs (layers 1,2).
// =====================================================================
__global__ __launch_bounds__(256, 4) void mfma_gemm(
    const unsigned short* __restrict__ hb,
    const unsigned short* __restrict__ Wp,
    const float* __restrict__ bs_all,
    const float* __restrict__ bd_all,
    unsigned short* __restrict__ fs_all,
    unsigned short* __restrict__ fd_all,
    int nrb, int n)
{
    __shared__ char lsA[4096];
    __shared__ char lsC[8192];

    const int tid = threadIdx.x;
    const int wave = tid >> 6, lane = tid & 63;
    const int r = blockIdx.x & 3;
    const int half = wave & 1;
    const int mat  = wave >> 1;
    const int lo = lane & 15, quad = lane >> 4;

    const unsigned short* Wr = Wp + (size_t)r * 2 * FF * FF;
    const float* bp = mat ? bd_all : bs_all;
    unsigned short* fs = fs_all + (size_t)r * n * FF;
    unsigned short* fd = fd_all + (size_t)r * n * FF;

    f16x8 B[4][4];
    #pragma unroll
    for (int nbi = 0; nbi < 4; ++nbi)
        #pragma unroll
        for (int ks = 0; ks < 4; ++ks) {
            const int nb = half * 4 + nbi;
            B[nbi][ks] = *(const f16x8*)
                &Wr[(((((size_t)mat * 8 + nb) * 4 + ks) * 64 + lane) * 8)];
        }

    float bias[4];
    #pragma unroll
    for (int nbi = 0; nbi < 4; ++nbi)
        bias[nbi] = bp[r * FF + (half * 4 + nbi) * 16 + lo];

    const int srow = tid >> 4, schunk = tid & 15;
    const int stride = gridDim.x >> 2;
    for (int rb = blockIdx.x >> 2; rb < nrb; rb += stride) {
        const int row0 = rb * 16;

        {
            const uint4 g = *(const uint4*)&hb[(size_t)row0 * FF + tid * 8];
            *(uint4*)&lsA[swz16(srow, schunk)] = g;
        }
        __syncthreads();

        f16x8 A[4];
        #pragma unroll
        for (int ks = 0; ks < 4; ++ks)
            A[ks] = *(const f16x8*)&lsA[swz16(lo, ks * 4 + quad)];

        f4v c[4];
        #pragma unroll
        for (int nbi = 0; nbi < 4; ++nbi)
            c[nbi] = (f4v){bias[nbi], bias[nbi], bias[nbi], bias[nbi]};

        #pragma unroll
        for (int ks = 0; ks < 4; ++ks)
            #pragma unroll
            for (int nbi = 0; nbi < 4; ++nbi)
                c[nbi] = __builtin_amdgcn_mfma_f32_16x16x32_f16(
                    A[ks], B[nbi][ks], c[nbi], 0, 0, 0);

        #pragma unroll
        for (int nbi = 0; nbi < 4; ++nbi)
            #pragma unroll
            for (int i = 0; i < 4; ++i) {
                const int row = quad * 4 + i;
                const int cb  = ((half * 4 + nbi) * 16 + lo) * 2;
                *(unsigned short*)&lsC[mat * 4096 + swz16(row, cb >> 4) + (cb & 15)]
                    = f2h(c[nbi][i]);
            }
        __syncthreads();

        #pragma unroll
        for (int p = 0; p < 2; ++p) {
            const int unit = p * 256 + tid;
            const int m    = unit >> 8;
            const int row  = (unit >> 4) & 15;
            const int ch   = unit & 15;
            const uint4 d = *(const uint4*)&lsC[m * 4096 + swz16(row, ch)];
            unsigned short* out = m ? fd : fs;
            *(uint4*)&out[(size_t)(row0 + row) * FF + ch * 8] = d;
        }
        __syncthreads();
    }
}

// =====================================================================
// Fused aggregate, quarter-wave per edge. R18: plane-major slots --
// each lane loads its quarter's slot entry directly (qsel deleted).
// =====================================================================
__device__ __forceinline__ void edge4(
    uint4 g, bool ok, const half2v* fdv, const half2v* atv,
    float& den, half2v* acc)
{
    const half2v C02 = {(_Float16)0.2f, (_Float16)0.2f};
    half2v f[4] = {u2h(g.x), u2h(g.y), u2h(g.z), u2h(g.w)};
    float v = 0.f;
    #pragma unroll
    for (int i = 0; i < 4; ++i) {
        const half2v z = f[i] + fdv[i];
        const half2v l = __builtin_elementwise_max(z, z * C02);
        v = dot2(l, atv[i], v);
    }
    v += __shfl_xor(v, 2);
    v += __shfl_xor(v, 1);
    const float e = ok ? __expf(v) : 0.f;
    den += e;
    const half2v eh = pk2h(e);
    #pragma unroll
    for (int i = 0; i < 4; ++i) acc[i] += eh * f[i];
}

__global__ __launch_bounds__(256) void aggregate(
    const int* __restrict__ cnt,             // [R*n]
    const int* __restrict__ slots,           // [CAP][R*n] plane-major
    const unsigned* __restrict__ fs_all,     // [R][n][64] f16 pairs
    const unsigned* __restrict__ fd_all,
    const unsigned* __restrict__ att_h,      // this layer: [R][64] f16 pairs
    unsigned* __restrict__ out_h,            // [n][64] or null
    float* __restrict__ out_f32,             // [n][32] or null
    int n)
{
    const int node = blockIdx.x * 4 + (threadIdx.x >> 6);
    if (node >= n) return;
    const int lane = threadIdx.x & 63;
    const int quarter = lane >> 4;
    const int q = lane & 15;
    const int fo = 4 * q;
    const int L4 = n << 2;

    int m[4], i0[4];
    #pragma unroll
    for (int r = 0; r < 4; ++r) {
        const int rd = r * n + node;
        m[r]  = cnt[rd];
        i0[r] = slots[(size_t)quarter * L4 + rd];   // this lane's edge (p = quarter)
    }

    half2v val[4];
    #pragma unroll
    for (int i = 0; i < 4; ++i) val[i] = (half2v){(_Float16)0.f, (_Float16)0.f};

    #pragma unroll
    for (int rp = 0; rp < 2; ++rp) {
        const int ra = 2 * rp, rb = 2 * rp + 1;
        const int rdA = ra * n + node;
        const int rdB = rb * n + node;
        const int mA = m[ra], mB = m[rb];
        const unsigned* fsuA = fs_all + (size_t)ra * n * 64;
        const unsigned* fsuB = fs_all + (size_t)rb * n * 64;

        // ---- issue ALL loads for both relations up front ----
        const int sA1 = slots[(size_t)(4 + quarter) * L4 + rdA];
        const int sB1 = slots[(size_t)(4 + quarter) * L4 + rdB];
        const uint4 ufdA = *(const uint4*)&fd_all[(size_t)rdA * 64 + fo];
        const uint4 ufdB = *(const uint4*)&fd_all[(size_t)rdB * 64 + fo];
        const uint4 uatA = *(const uint4*)&att_h[ra * 64 + fo];
        const uint4 uatB = *(const uint4*)&att_h[rb * 64 + fo];

        const bool okA0 = quarter < mA, okA1 = 4 + quarter < mA;
        const bool okB0 = quarter < mB, okB1 = 4 + quarter < mB;
        int iA0 = okA0 ? i0[ra] : 0;
        int iB0 = okB0 ? i0[rb] : 0;
        int iA1 = okA1 ? sA1 : 0;
        int iB1 = okB1 ? sB1 : 0;
        const uint4 gA0 = *(const uint4*)&fsuA[(size_t)iA0 * 64 + fo];
        const uint4 gB0 = *(const uint4*)&fsuB[(size_t)iB0 * 64 + fo];
        const uint4 gA1 = *(const uint4*)&fsuA[(size_t)iA1 * 64 + fo];
        const uint4 gB1 = *(const uint4*)&fsuB[(size_t)iB1 * 64 + fo];

        half2v fdvA[4] = {u2h(ufdA.x), u2h(ufdA.y), u2h(ufdA.z), u2h(ufdA.w)};
        half2v atvA[4] = {u2h(uatA.x), u2h(uatA.y), u2h(uatA.z), u2h(uatA.w)};
        half2v fdvB[4] = {u2h(ufdB.x), u2h(ufdB.y), u2h(ufdB.z), u2h(ufdB.w)};
        half2v atvB[4] = {u2h(uatB.x), u2h(uatB.y), u2h(uatB.z), u2h(uatB.w)};

        float denA = 0.f, denB = 0.f;
        half2v accA[4], accB[4];
        #pragma unroll
        for (int i = 0; i < 4; ++i) {
            accA[i] = (half2v){(_Float16)0.f, (_Float16)0.f};
            accB[i] = (half2v){(_Float16)0.f, (_Float16)0.f};
        }

        edge4(gA0, okA0, fdvA, atvA, denA, accA);
        edge4(gB0, okB0, fdvB, atvB, denB, accB);
        if (mA > 4) edge4(gA1, okA1, fdvA, atvA, denA, accA);
        if (mB > 4) edge4(gB1, okB1, fdvB, atvB, denB, accB);

        if (mA > 8) {                        // P ~ 2%
            for (int p = 8; p < mA; p += 4) {
                const int ei = p + quarter;
                const bool ok = ei < mA;
                int s = slots[(size_t)(ei < CAP ? ei : CAP - 1) * L4 + rdA];
                s = ok ? s : 0;
                const uint4 g = *(const uint4*)&fsuA[(size_t)s * 64 + fo];
                edge4(g, ok, fdvA, atvA, denA, accA);
            }
        }
        if (mB > 8) {
            for (int p = 8; p < mB; p += 4) {
                const int ei = p + quarter;
                const bool ok = ei < mB;
                int s = slots[(size_t)(ei < CAP ? ei : CAP - 1) * L4 + rdB];
                s = ok ? s : 0;
                const uint4 g = *(const uint4*)&fsuB[(size_t)s * 64 + fo];
                edge4(g, ok, fdvB, atvB, denB, accB);
            }
        }

        if (mA) {
            denA += __shfl_xor(denA, 16);
            denA += __shfl_xor(denA, 32);
            const half2v ih = pk2h(__builtin_amdgcn_rcpf(denA));   // denA > 0
            #pragma unroll
            for (int i = 0; i < 4; ++i) val[i] += accA[i] * ih;
        }
        if (mB) {
            denB += __shfl_xor(denB, 16);
            denB += __shfl_xor(denB, 32);
            const half2v ih = pk2h(__builtin_amdgcn_rcpf(denB));   // denB > 0
            #pragma unroll
            for (int i = 0; i < 4; ++i) val[i] += accB[i] * ih;
        }
    }

    // combine quarters' numerator contributions (packed)
    #pragma unroll
    for (int i = 0; i < 4; ++i) {
        val[i] = shfladd_h(val[i], 16);
        val[i] = shfladd_h(val[i], 32);
    }

    if (out_f32) {
        // mean over heads: lane q holds feats 8q..8q+7, head = q>>2;
        // orbit masks 4, 8 (packed)
        #pragma unroll
        for (int i = 0; i < 4; ++i) {
            val[i] = shfladd_h(val[i], 4);
            val[i] = shfladd_h(val[i], 8);
        }
        if (lane < 4) {
            float* o = &out_f32[(size_t)node * 32 + 8 * lane];
            *(float4*)&o[0] = make_float4(0.25f * (float)val[0].x, 0.25f * (float)val[0].y,
                                          0.25f * (float)val[1].x, 0.25f * (float)val[1].y);
            *(float4*)&o[4] = make_float4(0.25f * (float)val[2].x, 0.25f * (float)val[2].y,
                                          0.25f * (float)val[3].x, 0.25f * (float)val[3].y);
        }
    } else {
        if (lane < 16) {
            uint4 o;
            o.x = h2u(val[0]); o.y = h2u(val[1]);
            o.z = h2u(val[2]); o.w = h2u(val[3]);
            *(uint4*)&out_h[(size_t)node * 64 + fo] = o;
        }
    }
}

// =====================================================================
extern "C" void kernel_launch(void* const* d_in, const int* in_sizes, int n_in,
                              void* d_out, int out_size, void* d_ws, size_t ws_size,
                              hipStream_t stream)
{
    const int n  = in_sizes[0] / FF;     // 50000
    const int R  = 4;
    const int ne = in_sizes[1] / R;      // 200000
    const int totalE = R * ne;
    const int L  = R * n;
    const int nrb = (n + 15) / 16;

    const float* x    = (const float*)d_in[0];
    const int*   esrc = (const int*)d_in[1];
    const int*   edst = (const int*)d_in[2];

    // ---- workspace layout (~142 MB of ~268 MB ws) ----
    char* p = (char*)d_ws;
    auto carve = [&p](size_t bytes) { char* q = p; p += (bytes + 255) & ~(size_t)255; return q; };
    unsigned*       hbA    = (unsigned*)      carve((size_t)n * 64 * 4);
    unsigned*       hbB    = (unsigned*)      carve((size_t)n * 64 * 4);
    unsigned short* fs_all = (unsigned short*)carve((size_t)R * n * FF * 2);
    unsigned short* fd_all = (unsigned short*)carve((size_t)R * n * FF * 2);
    unsigned short* Wp     = (unsigned short*)carve((size_t)3 * R * 2 * FF * FF * 2);
    unsigned*       attH   = (unsigned*)      carve((size_t)3 * R * 64 * 4);
    int*            cursor = (int*)           carve((size_t)L * 4);
    int*            slots  = (int*)           carve((size_t)L * CAP * 4);   // [CAP][L] plane-major

    (void)hipMemsetAsync(cursor, 0, (size_t)L * sizeof(int), stream);

    // ---- phase 1: CSR fill + pack W + pack att ----
    const int CB = (totalE + 1023) / 1024;
    csr_pack<<<CB + 1536 + 3, 256, 0, stream>>>(
        esrc, edst, cursor, slots, totalE, ne, n,
        (const float*)d_in[3],  (const float*)d_in[5],
        (const float*)d_in[8],  (const float*)d_in[10],
        (const float*)d_in[13], (const float*)d_in[15],
        Wp,
        (const float*)d_in[7], (const float*)d_in[12], (const float*)d_in[17],
        attH, CB);

    // ---- phase 2: layer-0 GEMM from packed Wp ----
    gemm0<<<G0, 256, 0, stream>>>(
        x, Wp,
        (const float*)d_in[4], (const float*)d_in[6],
        fs_all, fd_all, nrb, n);

    // ---- layers ----
    unsigned* bufs[3] = {hbA, hbB, nullptr};
    for (int l = 0; l < 3; ++l) {
        if (l > 0) {
            const float* bsrc = (const float*)d_in[3 + 5 * l + 1];
            const float* bdst = (const float*)d_in[3 + 5 * l + 3];
            mfma_gemm<<<GG, 256, 0, stream>>>(
                (const unsigned short*)bufs[l - 1],
                Wp + (size_t)l * R * 2 * FF * FF,
                bsrc, bdst, fs_all, fd_all, nrb, n);
        }
        const int last = (l == 2);
        aggregate<<<(n + 3) / 4, 256, 0, stream>>>(
            cursor, slots,
            (const unsigned*)fs_all, (const unsigned*)fd_all,
            attH + (size_t)l * R * 64,
            last ? nullptr : bufs[l],
            last ? (float*)d_out : nullptr, n);
    }
}

// Round 6
// 373.768 us; speedup vs baseline: 1.1742x; 1.0943x over previous
//
#include <hip/hip_runtime.h>
#include <math.h>

#define FF 128     // feature width (all layers)
#define G0F 1024   // gemm0 blocks inside fused2 (4/CU tail)
#define GG 2048    // mfma_gemm grid

typedef _Float16 half2v __attribute__((ext_vector_type(2)));
typedef _Float16 f16x8  __attribute__((ext_vector_type(8)));
typedef __fp16   fp16x2 __attribute__((ext_vector_type(2)));
typedef __attribute__((ext_vector_type(4))) float f4v;

__device__ __forceinline__ half2v u2h(unsigned u) {
    union { unsigned u; half2v h; } c; c.u = u; return c.h;
}
__device__ __forceinline__ unsigned h2u(half2v h) {
    union { unsigned u; half2v h; } c; c.h = h; return c.u;
}
__device__ __forceinline__ unsigned short f2h(float f) {
    _Float16 h = (_Float16)f;
    unsigned short u; __builtin_memcpy(&u, &h, 2); return u;
}
__device__ __forceinline__ half2v pk2h(float e) {
    union { fp16x2 p; half2v h; } c;
    c.p = __builtin_amdgcn_cvt_pkrtz(e, e);
    return c.h;
}
__device__ __forceinline__ float dot2(half2v a, half2v b, float c) {
#if __has_builtin(__builtin_amdgcn_fdot2)
    union { half2v h; fp16x2 p; } ca, cb;
    ca.h = a; cb.h = b;
    return __builtin_amdgcn_fdot2(ca.p, cb.p, c, false);
#else
    return c + (float)a.x * (float)b.x + (float)a.y * (float)b.y;
#endif
}
__device__ __forceinline__ half2v shfladd_h(half2v v, int mask) {
    return v + u2h(__shfl_xor(h2u(v), mask));
}
// 16B-chunk XOR swizzle inside a [16 rows][256B] LDS tile.
__device__ __forceinline__ int swz16(int row, int chunk) {
    return row * 256 + (((chunk ^ row) & 15) << 4);
}

// =====================================================================
// R19. (a) CSR record layout: rec[rd] = 64B {cnt, s0..s14} + overflow
// planes -- R18 post-mortem: plane-major did NOT cut WRITE_SIZE (55MB);
// cross-XCD temporal scatter means every edge costs ~2 random line
// touches (cursor line + slot line) at the coherence point. Same-line
// record halves that. (b) csr + gemm0 re-overlapped in one dispatch
// (they serialize post-split; disjoint resources). W0-pack race removed
// by tiny pack0 pre-kernel so gemm0 reads packed Wp (cheap B-fill ->
// 1024 blocks OK, unlike R15's strided-gather replication).
// =====================================================================

// ---------------- pack0: pack W0 + att (tiny pre-kernel) -------------
__global__ __launch_bounds__(256) void pack0(
    const float* __restrict__ W0s_, const float* __restrict__ W0d_,
    unsigned short* __restrict__ Wp,
    const float* __restrict__ a0, const float* __restrict__ a1,
    const float* __restrict__ a2, unsigned* __restrict__ attH)
{
    int b = blockIdx.x;
    const int tid = threadIdx.x;
    if (b < 512) {                       // 4r x 2mat x 128 x 128 = 131072
        const int t = b * 256 + tid;
        const int r   = t >> 15;
        const int mat = (t >> 14) & 1;
        const int idx = t & 16383;
        const int k = idx >> 7, nn = idx & 127;
        const float* W = mat ? W0d_ : W0s_;
        const float v = W[((size_t)r * FF + k) * FF + nn];
        const int nb = nn >> 4, lo = nn & 15;
        const int ks = k >> 5, quad = (k >> 3) & 3, j = k & 7;
        const int lane = quad * 16 + lo;
        const size_t o = ((((((size_t)r * 2 + mat) * 8 + nb) * 4 + ks) * 64 + lane) * 8) + j;
        Wp[o] = f2h(v);
        return;
    }
    b -= 512;
    const int t = b * 256 + tid;
    if (t >= 768) return;
    const int l = t >> 8, rest = t & 255;
    const float* a = (l == 0) ? a0 : (l == 1) ? a1 : a2;
    const float2 v = ((const float2*)a)[rest];
    half2v h = {(_Float16)v.x, (_Float16)v.y};
    attH[t] = h2u(h);
}

// ------- fused2: csr fill (record) + gemm0 + pack W1/W2 --------------
//   blocks [0, CB)              : CSR fill, 4 edges/thread
//   blocks [CB, CB+G0F)         : layer-0 GEMM from packed Wp
//   blocks [CB+G0F, +1024)      : pack W1, W2
__global__ __launch_bounds__(256, 4) void fused2(
    const int* __restrict__ esrc_all, const int* __restrict__ edst_all,
    int* __restrict__ rec, int* __restrict__ ovf,
    int totalE, int ne, int n, int CB,
    const float* __restrict__ x,
    const unsigned short* __restrict__ Wp,
    const float* __restrict__ bs0, const float* __restrict__ bd0,
    unsigned short* __restrict__ fs_all, unsigned short* __restrict__ fd_all,
    int nrb,
    const float* __restrict__ W1s_, const float* __restrict__ W1d_,
    const float* __restrict__ W2s_, const float* __restrict__ W2d_,
    unsigned short* __restrict__ Wp_full)
{
    __shared__ char lsA[4096];
    __shared__ char lsC[8192];

    int b = blockIdx.x;
    const int tid = threadIdx.x;
    const int L = n << 2;

    if (b < CB) {
        // ---- padded-CSR fill, record layout, 4 chains/thread ----
        const int t0 = b * 1024 + tid;
        #pragma unroll
        for (int k = 0; k < 4; ++k) {
            const int i = t0 + k * 256;
            if (i < totalE) {
                const int r = i / ne;
                const int rd = r * n + edst_all[i];
                const int src = esrc_all[i];
                const int idx = atomicAdd(&rec[(size_t)rd * 16], 1);
                if (idx < 15)      rec[(size_t)rd * 16 + 1 + idx] = src;
                else if (idx < 32) ovf[(size_t)(idx - 15) * L + rd] = src;
            }
        }
        return;
    }
    b -= CB;

    if (b < G0F) {
        // ---- layer-0 GEMM (f32 x, packed-Wp B), LDS-staged ----
        const int wave = tid >> 6, lane = tid & 63;
        const int r = b & 3;
        const int half = wave & 1;
        const int mat  = wave >> 1;
        const int lo = lane & 15, quad = lane >> 4;

        const unsigned short* Wr = Wp + (size_t)r * 2 * FF * FF;
        const float* bp = mat ? bd0 : bs0;
        unsigned short* fs = fs_all + (size_t)r * n * FF;
        unsigned short* fd = fd_all + (size_t)r * n * FF;

        f16x8 B[4][4];
        #pragma unroll
        for (int nbi = 0; nbi < 4; ++nbi)
            #pragma unroll
            for (int ks = 0; ks < 4; ++ks) {
                const int nb = half * 4 + nbi;
                B[nbi][ks] = *(const f16x8*)
                    &Wr[(((((size_t)mat * 8 + nb) * 4 + ks) * 64 + lane) * 8)];
            }

        float bias[4];
        #pragma unroll
        for (int nbi = 0; nbi < 4; ++nbi)
            bias[nbi] = bp[r * FF + (half * 4 + nbi) * 16 + lo];

        const int srow = tid >> 4, schunk = tid & 15;
        const int stride = G0F >> 2;
        for (int rb = b >> 2; rb < nrb; rb += stride) {
            const int row0 = rb * 16;
            {
                const float* xs = &x[(size_t)row0 * FF + tid * 8];
                const float4 p0 = *(const float4*)&xs[0];
                const float4 p1 = *(const float4*)&xs[4];
                f16x8 v;
                v[0] = (_Float16)p0.x; v[1] = (_Float16)p0.y;
                v[2] = (_Float16)p0.z; v[3] = (_Float16)p0.w;
                v[4] = (_Float16)p1.x; v[5] = (_Float16)p1.y;
                v[6] = (_Float16)p1.z; v[7] = (_Float16)p1.w;
                *(f16x8*)&lsA[swz16(srow, schunk)] = v;
            }
            __syncthreads();

            f16x8 A[4];
            #pragma unroll
            for (int ks = 0; ks < 4; ++ks)
                A[ks] = *(const f16x8*)&lsA[swz16(lo, ks * 4 + quad)];

            f4v c[4];
            #pragma unroll
            for (int nbi = 0; nbi < 4; ++nbi)
                c[nbi] = (f4v){bias[nbi], bias[nbi], bias[nbi], bias[nbi]};

            #pragma unroll
            for (int ks = 0; ks < 4; ++ks)
                #pragma unroll
                for (int nbi = 0; nbi < 4; ++nbi)
                    c[nbi] = __builtin_amdgcn_mfma_f32_16x16x32_f16(
                        A[ks], B[nbi][ks], c[nbi], 0, 0, 0);

            #pragma unroll
            for (int nbi = 0; nbi < 4; ++nbi)
                #pragma unroll
                for (int i = 0; i < 4; ++i) {
                    const int row = quad * 4 + i;
                    const int cb  = ((half * 4 + nbi) * 16 + lo) * 2;
                    *(unsigned short*)&lsC[mat * 4096 + swz16(row, cb >> 4) + (cb & 15)]
                        = f2h(c[nbi][i]);
                }
            __syncthreads();

            #pragma unroll
            for (int p = 0; p < 2; ++p) {
                const int unit = p * 256 + tid;
                const int m    = unit >> 8;
                const int row  = (unit >> 4) & 15;
                const int ch   = unit & 15;
                const uint4 d = *(const uint4*)&lsC[m * 4096 + swz16(row, ch)];
                unsigned short* out = m ? fd : fs;
                *(uint4*)&out[(size_t)(row0 + row) * FF + ch * 8] = d;
            }
            __syncthreads();
        }
        return;
    }
    b -= G0F;

    // ---- pack W for layers 1,2 ----
    const int t = b * 256 + tid;
    if (t >= 2 * 4 * 2 * FF * FF) return;
    const int l    = 1 + (t >> 17);
    const int rest = t & 131071;
    const int r    = rest >> 15;
    const int mat  = (rest >> 14) & 1;
    const int idx  = rest & 16383;
    const int k = idx >> 7, nn = idx & 127;
    const float* W = (l == 1) ? (mat ? W1d_ : W1s_)
                              : (mat ? W2d_ : W2s_);
    const float v = W[((size_t)r * FF + k) * FF + nn];
    const int nb = nn >> 4, lo = nn & 15;
    const int ks = k >> 5, quad = (k >> 3) & 3, j = k & 7;
    const int lane = quad * 16 + lo;
    const size_t o = (((((((size_t)l * 4 + r) * 2 + mat) * 8 + nb) * 4 + ks) * 64 + lane) * 8) + j;
    Wp_full[o] = f2h(v);
}

// =====================================================================
// Batched MFMA GEMM over all 4 relations, f16 inputs (layers 1,2).
// =====================================================================
__global__ __launch_bounds__(256, 4) void mfma_gemm(
    const unsigned short* __restrict__ hb,
    const unsigned short* __restrict__ Wp,
    const float* __restrict__ bs_all,
    const float* __restrict__ bd_all,
    unsigned short* __restrict__ fs_all,
    unsigned short* __restrict__ fd_all,
    int nrb, int n)
{
    __shared__ char lsA[4096];
    __shared__ char lsC[8192];

    const int tid = threadIdx.x;
    const int wave = tid >> 6, lane = tid & 63;
    const int r = blockIdx.x & 3;
    const int half = wave & 1;
    const int mat  = wave >> 1;
    const int lo = lane & 15, quad = lane >> 4;

    const unsigned short* Wr = Wp + (size_t)r * 2 * FF * FF;
    const float* bp = mat ? bd_all : bs_all;
    unsigned short* fs = fs_all + (size_t)r * n * FF;
    unsigned short* fd = fd_all + (size_t)r * n * FF;

    f16x8 B[4][4];
    #pragma unroll
    for (int nbi = 0; nbi < 4; ++nbi)
        #pragma unroll
        for (int ks = 0; ks < 4; ++ks) {
            const int nb = half * 4 + nbi;
            B[nbi][ks] = *(const f16x8*)
                &Wr[(((((size_t)mat * 8 + nb) * 4 + ks) * 64 + lane) * 8)];
        }

    float bias[4];
    #pragma unroll
    for (int nbi = 0; nbi < 4; ++nbi)
        bias[nbi] = bp[r * FF + (half * 4 + nbi) * 16 + lo];

    const int srow = tid >> 4, schunk = tid & 15;
    const int stride = gridDim.x >> 2;
    for (int rb = blockIdx.x >> 2; rb < nrb; rb += stride) {
        const int row0 = rb * 16;
        {
            const uint4 g = *(const uint4*)&hb[(size_t)row0 * FF + tid * 8];
            *(uint4*)&lsA[swz16(srow, schunk)] = g;
        }
        __syncthreads();

        f16x8 A[4];
        #pragma unroll
        for (int ks = 0; ks < 4; ++ks)
            A[ks] = *(const f16x8*)&lsA[swz16(lo, ks * 4 + quad)];

        f4v c[4];
        #pragma unroll
        for (int nbi = 0; nbi < 4; ++nbi)
            c[nbi] = (f4v){bias[nbi], bias[nbi], bias[nbi], bias[nbi]};

        #pragma unroll
        for (int ks = 0; ks < 4; ++ks)
            #pragma unroll
            for (int nbi = 0; nbi < 4; ++nbi)
                c[nbi] = __builtin_amdgcn_mfma_f32_16x16x32_f16(
                    A[ks], B[nbi][ks], c[nbi], 0, 0, 0);

        #pragma unroll
        for (int nbi = 0; nbi < 4; ++nbi)
            #pragma unroll
            for (int i = 0; i < 4; ++i) {
                const int row = quad * 4 + i;
                const int cb  = ((half * 4 + nbi) * 16 + lo) * 2;
                *(unsigned short*)&lsC[mat * 4096 + swz16(row, cb >> 4) + (cb & 15)]
                    = f2h(c[nbi][i]);
            }
        __syncthreads();

        #pragma unroll
        for (int p = 0; p < 2; ++p) {
            const int unit = p * 256 + tid;
            const int m    = unit >> 8;
            const int row  = (unit >> 4) & 15;
            const int ch   = unit & 15;
            const uint4 d = *(const uint4*)&lsC[m * 4096 + swz16(row, ch)];
            unsigned short* out = m ? fd : fs;
            *(uint4*)&out[(size_t)(row0 + row) * FF + ch * 8] = d;
        }
        __syncthreads();
    }
}

// =====================================================================
// Fused aggregate, quarter-wave per edge. R19: CSR record reads --
// cnt + slot words for a (r,node) come from ONE 64B line.
// =====================================================================
__device__ __forceinline__ void edge4(
    uint4 g, bool ok, const half2v* fdv, const half2v* atv,
    float& den, half2v* acc)
{
    const half2v C02 = {(_Float16)0.2f, (_Float16)0.2f};
    half2v f[4] = {u2h(g.x), u2h(g.y), u2h(g.z), u2h(g.w)};
    float v = 0.f;
    #pragma unroll
    for (int i = 0; i < 4; ++i) {
        const half2v z = f[i] + fdv[i];
        const half2v l = __builtin_elementwise_max(z, z * C02);
        v = dot2(l, atv[i], v);
    }
    v += __shfl_xor(v, 2);
    v += __shfl_xor(v, 1);
    const float e = ok ? __expf(v) : 0.f;
    den += e;
    const half2v eh = pk2h(e);
    #pragma unroll
    for (int i = 0; i < 4; ++i) acc[i] += eh * f[i];
}

__global__ __launch_bounds__(256) void aggregate(
    const int* __restrict__ rec,             // [R*n][16] {cnt, s0..s14}
    const int* __restrict__ ovf,             // [17][R*n] planes, idx 15..31
    const unsigned* __restrict__ fs_all,     // [R][n][64] f16 pairs
    const unsigned* __restrict__ fd_all,
    const unsigned* __restrict__ att_h,      // this layer: [R][64] f16 pairs
    unsigned* __restrict__ out_h,            // [n][64] or null
    float* __restrict__ out_f32,             // [n][32] or null
    int n)
{
    const int node = blockIdx.x * 4 + (threadIdx.x >> 6);
    if (node >= n) return;
    const int lane = threadIdx.x & 63;
    const int quarter = lane >> 4;
    const int q = lane & 15;
    const int fo = 4 * q;
    const int L = n << 2;

    int m[4], i0[4], i1[4];
    #pragma unroll
    for (int r = 0; r < 4; ++r) {
        const int rd = r * n + node;
        const int* rp = &rec[(size_t)rd * 16];
        m[r]  = rp[0];
        i0[r] = rp[1 + quarter];
        i1[r] = rp[5 + quarter];
    }

    half2v val[4];
    #pragma unroll
    for (int i = 0; i < 4; ++i) val[i] = (half2v){(_Float16)0.f, (_Float16)0.f};

    #pragma unroll
    for (int rp2 = 0; rp2 < 2; ++rp2) {
        const int ra = 2 * rp2, rb = 2 * rp2 + 1;
        const int rdA = ra * n + node;
        const int rdB = rb * n + node;
        const int mA = m[ra], mB = m[rb];
        const unsigned* fsuA = fs_all + (size_t)ra * n * 64;
        const unsigned* fsuB = fs_all + (size_t)rb * n * 64;

        const uint4 ufdA = *(const uint4*)&fd_all[(size_t)rdA * 64 + fo];
        const uint4 ufdB = *(const uint4*)&fd_all[(size_t)rdB * 64 + fo];
        const uint4 uatA = *(const uint4*)&att_h[ra * 64 + fo];
        const uint4 uatB = *(const uint4*)&att_h[rb * 64 + fo];

        const bool okA0 = quarter < mA, okA1 = 4 + quarter < mA;
        const bool okB0 = quarter < mB, okB1 = 4 + quarter < mB;
        int iA0 = okA0 ? i0[ra] : 0;
        int iB0 = okB0 ? i0[rb] : 0;
        int iA1 = okA1 ? i1[ra] : 0;
        int iB1 = okB1 ? i1[rb] : 0;
        const uint4 gA0 = *(const uint4*)&fsuA[(size_t)iA0 * 64 + fo];
        const uint4 gB0 = *(const uint4*)&fsuB[(size_t)iB0 * 64 + fo];
        const uint4 gA1 = *(const uint4*)&fsuA[(size_t)iA1 * 64 + fo];
        const uint4 gB1 = *(const uint4*)&fsuB[(size_t)iB1 * 64 + fo];

        half2v fdvA[4] = {u2h(ufdA.x), u2h(ufdA.y), u2h(ufdA.z), u2h(ufdA.w)};
        half2v atvA[4] = {u2h(uatA.x), u2h(uatA.y), u2h(uatA.z), u2h(uatA.w)};
        half2v fdvB[4] = {u2h(ufdB.x), u2h(ufdB.y), u2h(ufdB.z), u2h(ufdB.w)};
        half2v atvB[4] = {u2h(uatB.x), u2h(uatB.y), u2h(uatB.z), u2h(uatB.w)};

        float denA = 0.f, denB = 0.f;
        half2v accA[4], accB[4];
        #pragma unroll
        for (int i = 0; i < 4; ++i) {
            accA[i] = (half2v){(_Float16)0.f, (_Float16)0.f};
            accB[i] = (half2v){(_Float16)0.f, (_Float16)0.f};
        }

        edge4(gA0, okA0, fdvA, atvA, denA, accA);
        edge4(gB0, okB0, fdvB, atvB, denB, accB);
        if (mA > 4) edge4(gA1, okA1, fdvA, atvA, denA, accA);
        if (mB > 4) edge4(gB1, okB1, fdvB, atvB, denB, accB);

        if (mA > 8) {                        // P ~ 2%
            for (int p = 8; p < mA; p += 4) {
                const int ei = p + quarter;
                const bool ok = ei < mA;
                const int eic = ei < 31 ? ei : 31;
                int s = (eic < 15) ? rec[(size_t)rdA * 16 + 1 + eic]
                                   : ovf[(size_t)(eic - 15) * L + rdA];
                s = ok ? s : 0;
                const uint4 g = *(const uint4*)&fsuA[(size_t)s * 64 + fo];
                edge4(g, ok, fdvA, atvA, denA, accA);
            }
        }
        if (mB > 8) {
            for (int p = 8; p < mB; p += 4) {
                const int ei = p + quarter;
                const bool ok = ei < mB;
                const int eic = ei < 31 ? ei : 31;
                int s = (eic < 15) ? rec[(size_t)rdB * 16 + 1 + eic]
                                   : ovf[(size_t)(eic - 15) * L + rdB];
                s = ok ? s : 0;
                const uint4 g = *(const uint4*)&fsuB[(size_t)s * 64 + fo];
                edge4(g, ok, fdvB, atvB, denB, accB);
            }
        }

        if (mA) {
            denA += __shfl_xor(denA, 16);
            denA += __shfl_xor(denA, 32);
            const half2v ih = pk2h(__builtin_amdgcn_rcpf(denA));   // denA > 0
            #pragma unroll
            for (int i = 0; i < 4; ++i) val[i] += accA[i] * ih;
        }
        if (mB) {
            denB += __shfl_xor(denB, 16);
            denB += __shfl_xor(denB, 32);
            const half2v ih = pk2h(__builtin_amdgcn_rcpf(denB));   // denB > 0
            #pragma unroll
            for (int i = 0; i < 4; ++i) val[i] += accB[i] * ih;
        }
    }

    // combine quarters' numerator contributions (packed)
    #pragma unroll
    for (int i = 0; i < 4; ++i) {
        val[i] = shfladd_h(val[i], 16);
        val[i] = shfladd_h(val[i], 32);
    }

    if (out_f32) {
        // mean over heads: lane q holds feats 8q..8q+7, head = q>>2
        #pragma unroll
        for (int i = 0; i < 4; ++i) {
            val[i] = shfladd_h(val[i], 4);
            val[i] = shfladd_h(val[i], 8);
        }
        if (lane < 4) {
            float* o = &out_f32[(size_t)node * 32 + 8 * lane];
            *(float4*)&o[0] = make_float4(0.25f * (float)val[0].x, 0.25f * (float)val[0].y,
                                          0.25f * (float)val[1].x, 0.25f * (float)val[1].y);
            *(float4*)&o[4] = make_float4(0.25f * (float)val[2].x, 0.25f * (float)val[2].y,
                                          0.25f * (float)val[3].x, 0.25f * (float)val[3].y);
        }
    } else {
        if (lane < 16) {
            uint4 o;
            o.x = h2u(val[0]); o.y = h2u(val[1]);
            o.z = h2u(val[2]); o.w = h2u(val[3]);
            *(uint4*)&out_h[(size_t)node * 64 + fo] = o;
        }
    }
}

// =====================================================================
extern "C" void kernel_launch(void* const* d_in, const int* in_sizes, int n_in,
                              void* d_out, int out_size, void* d_ws, size_t ws_size,
                              hipStream_t stream)
{
    const int n  = in_sizes[0] / FF;     // 50000
    const int R  = 4;
    const int ne = in_sizes[1] / R;      // 200000
    const int totalE = R * ne;
    const int L  = R * n;
    const int nrb = (n + 15) / 16;

    const float* x    = (const float*)d_in[0];
    const int*   esrc = (const int*)d_in[1];
    const int*   edst = (const int*)d_in[2];

    // ---- workspace layout ----
    char* p = (char*)d_ws;
    auto carve = [&p](size_t bytes) { char* q = p; p += (bytes + 255) & ~(size_t)255; return q; };
    unsigned*       hbA    = (unsigned*)      carve((size_t)n * 64 * 4);
    unsigned*       hbB    = (unsigned*)      carve((size_t)n * 64 * 4);
    unsigned short* fs_all = (unsigned short*)carve((size_t)R * n * FF * 2);
    unsigned short* fd_all = (unsigned short*)carve((size_t)R * n * FF * 2);
    unsigned short* Wp     = (unsigned short*)carve((size_t)3 * R * 2 * FF * FF * 2);
    unsigned*       attH   = (unsigned*)      carve((size_t)3 * R * 64 * 4);
    int*            rec    = (int*)           carve((size_t)L * 16 * 4);   // 64B records
    int*            ovf    = (int*)           carve((size_t)17 * L * 4);   // idx 15..31

    (void)hipMemsetAsync(rec, 0, (size_t)L * 16 * sizeof(int), stream);

    // ---- pack W0 + att (removes fused2's Wp race for layer 0) ----
    pack0<<<515, 256, 0, stream>>>(
        (const float*)d_in[3], (const float*)d_in[5], Wp,
        (const float*)d_in[7], (const float*)d_in[12], (const float*)d_in[17],
        attH);

    // ---- fused: csr fill + gemm0 + pack W1/W2 ----
    const int CB = (totalE + 1023) / 1024;
    fused2<<<CB + G0F + 1024, 256, 0, stream>>>(
        esrc, edst, rec, ovf, totalE, ne, n, CB,
        x, Wp,
        (const float*)d_in[4], (const float*)d_in[6],
        fs_all, fd_all, nrb,
        (const float*)d_in[8],  (const float*)d_in[10],
        (const float*)d_in[13], (const float*)d_in[15],
        Wp);

    // ---- layers ----
    unsigned* bufs[3] = {hbA, hbB, nullptr};
    for (int l = 0; l < 3; ++l) {
        if (l > 0) {
            const float* bsrc = (const float*)d_in[3 + 5 * l + 1];
            const float* bdst = (const float*)d_in[3 + 5 * l + 3];
            mfma_gemm<<<GG, 256, 0, stream>>>(
                (const unsigned short*)bufs[l - 1],
                Wp + (size_t)l * R * 2 * FF * FF,
                bsrc, bdst, fs_all, fd_all, nrb, n);
        }
        const int last = (l == 2);
        aggregate<<<(n + 3) / 4, 256, 0, stream>>>(
            rec, ovf,
            (const unsigned*)fs_all, (const unsigned*)fd_all,
            attH + (size_t)l * R * 64,
            last ? nullptr : bufs[l],
            last ? (float*)d_out : nullptr, n);
    }
}